// Round 16
// baseline (131.497 us; speedup 1.0000x reference)
//
#include <hip/hip_runtime.h>
#include <cstdint>
#include <cstddef>

// Problem constants (B=2, M=32, D=64, T=2048, F=16, L=512, S=32768)
#define DAMP 0.9998f

typedef __attribute__((ext_vector_type(8))) short bf16x8;
typedef __attribute__((ext_vector_type(4))) unsigned short u16x4;
typedef __attribute__((ext_vector_type(4))) float f32x4;

__device__ __forceinline__ unsigned short f2bf(float x) {
    unsigned u = __float_as_uint(x);
    unsigned r = (u + 0x7FFFu + ((u >> 16) & 1u)) >> 16;   // RNE
    return (unsigned short)r;
}
__device__ __forceinline__ float bf2f(unsigned short v) {
    return __uint_as_float((unsigned)v << 16);
}

// ---------------------------------------------------------------------------
// threefry2x32, JAX partitionable mode. key=(0,1); counter (0, j); o0^o1.
// [verified r4]
// ---------------------------------------------------------------------------
__device__ __forceinline__ void threefry_0j(unsigned j, unsigned& o0, unsigned& o1) {
    unsigned x0 = 0u;
    unsigned x1 = j + 1u;
    const unsigned ks2 = 0x1BD11BDBu;
#define TFR(r) { x0 += x1; x1 = (x1 << (r)) | (x1 >> (32 - (r))); x1 ^= x0; }
    TFR(13) TFR(15) TFR(26) TFR(6)
    x0 += 1u;   x1 += ks2 + 1u;
    TFR(17) TFR(29) TFR(16) TFR(24)
    x0 += ks2;  x1 += 0u + 2u;
    TFR(13) TFR(15) TFR(26) TFR(6)
    /*x0+=0*/   x1 += 1u + 3u;
    TFR(17) TFR(29) TFR(16) TFR(24)
    x0 += 1u;   x1 += ks2 + 4u;
    TFR(13) TFR(15) TFR(26) TFR(6)
    x0 += ks2;  x1 += 0u + 5u;
#undef TFR
    o0 = x0; o1 = x1;
}

__device__ __forceinline__ float noise_at(unsigned j) {
    unsigned o0, o1;
    threefry_0j(j, o0, o1);
    unsigned bits = o0 ^ o1;
    float u = __uint_as_float((bits >> 9) | 0x3F800000u) - 1.0f;
    return fmaxf(-1.0f, u * 2.0f - 1.0f);
}

// Dir(u) = sin(2049*pi*u/32768)/sin(pi*u/32768), Dir(0)=2049, period 32768.
__device__ __forceinline__ float dir_val(unsigned u) {
    if (u == 0u) return 2049.f;
    const float PIO = 9.58737992e-05f;
    unsigned y = (2049u * u) & 65535u;
    float sgn = 1.f;
    if (y >= 32768u) { y -= 32768u; sgn = -1.f; }
    unsigned yy = (y > 16384u) ? (32768u - y) : y;
    float sy = sgn * sinf((float)yy * PIO);
    unsigned uu = (u > 16384u) ? (32768u - u) : u;
    float su = sinf((float)uu * PIO);
    return sy / su;
}

// ---------------------------------------------------------------------------
// K1a: sim pass 1 + tables. Blocks [0,4096): 32-step chunk local affine
// constant w_c (r10-verified). Blocks [4096,4608): DirRev table. Blocks
// [4608,4640): normalized reversed filters.
// ---------------------------------------------------------------------------
__global__ __launch_bounds__(64) void sim_pass1(const float* __restrict__ forces,
                                                const float* __restrict__ hmod,
                                                const float* __restrict__ home,
                                                const float* __restrict__ masses,
                                                const float* __restrict__ tensions,
                                                float* __restrict__ w,
                                                const float* __restrict__ filters,
                                                unsigned short* __restrict__ dirrev,
                                                unsigned short* __restrict__ fnrev) {
    const int blk = blockIdx.x;
    const int d = threadIdx.x;
    if (blk >= 4608) {               // fnrev: 32 blocks x 64 threads
        const int row = blk - 4608;
        const float* src = filters + (size_t)row * 512;
        float s = 0.f;
        for (int i = d; i < 512; i += 64) { const float v = src[i]; s += v * v; }
        #pragma unroll
        for (int off = 32; off; off >>= 1) s += __shfl_xor(s, off);
        const float scale = 1.f / (sqrtf(s) + 1e-8f);
        for (int i = d; i < 512; i += 64)
            fnrev[(size_t)row * 512 + i] = f2bf(src[511 - i] * scale);
        return;
    }
    if (blk >= 4096) {               // dirrev: 512 blocks x 64 threads
        const unsigned i = (unsigned)(blk - 4096) * 64u + (unsigned)d;
        const unsigned p = i >> 11, k = i & 2047u;
        dirrev[i] = f2bf(dir_val(16u * (2047u - k) + p));
        return;
    }
    const int bm = blk >> 6, c = blk & 63;
    const int m = bm & 31;
    const int t0 = c * 32;
    __shared__ float kv[64];
    __shared__ float hv[64];
    __shared__ __align__(16) float gt[64][33];
    kv[d] = tensions[m * 64 + d] / masses[m];
    hv[d] = home[d];
    __syncthreads();
    for (int i = d; i < 512; i += 64) {
        const int dd = i >> 3, q = (i & 7) * 4;
        const size_t off = ((size_t)bm * 64 + dd) * 2048 + t0 + q;
        const float4 fv = *(const float4*)(forces + off);
        const float4 hm = *(const float4*)(hmod + off);
        const float kk = kv[dd], hh = hv[dd];
        float4 g;
        g.x = fmaf(kk, hh + hm.x, fv.x);
        g.y = fmaf(kk, hh + hm.y, fv.y);
        g.z = fmaf(kk, hh + hm.z, fv.z);
        g.w = fmaf(kk, hh + hm.w, fv.w);
        *(float4*)&gt[dd][q] = g;
    }
    __syncthreads();
    const float k = kv[d];
    float pos = 0.f, vel = 0.f;
    #pragma unroll 8
    for (int ts = 0; ts < 32; ++ts) {
        const float acc = fmaf(-k, pos, gt[d][ts]);
        vel = (vel + acc) * DAMP;
        pos = pos + vel;
    }
    float* wrow = w + (size_t)blk * 128;
    wrow[d] = pos; wrow[64 + d] = vel;
}

// ---------------------------------------------------------------------------
// K1b: sim scan — fp64 A^32, serial scan over 64 chunks per (bm,d).
// IN PLACE.  grid 64 (bm), 64 threads (d).  [r10-verified]
// ---------------------------------------------------------------------------
__global__ __launch_bounds__(64) void sim_scan(const float* __restrict__ masses,
                                               const float* __restrict__ tensions,
                                               float* __restrict__ w) {
    const int bm = blockIdx.x;
    const int m = bm & 31;
    const int d = threadIdx.x;
    const double kd = (double)(tensions[m * 64 + d] / masses[m]);
    const double cd = (double)DAMP;
    double Ma = 1.0 - cd * kd, Mb = cd, Mc = -cd * kd, Md = cd;
    #pragma unroll
    for (int it = 0; it < 5; ++it) {             // A^(2^5) = A^32
        const double na = Ma * Ma + Mb * Mc;
        const double nb = Ma * Mb + Mb * Md;
        const double nc = Mc * Ma + Md * Mc;
        const double nd = Mc * Mb + Md * Md;
        Ma = na; Mb = nb; Mc = nc; Md = nd;
    }
    double pos = 0.0, vel = 0.0;
    float* wb = w + (size_t)bm * 64 * 128;
    for (int c = 0; c < 64; ++c) {
        float* row = wb + c * 128;
        const double wp = (double)row[d];
        const double wv = (double)row[64 + d];
        row[d] = (float)pos;                     // entry state of chunk c
        row[64 + d] = (float)vel;
        const double np = Ma * pos + Mb * vel + wp;
        const double nv = Mc * pos + Md * vel + wv;
        pos = np; vel = nv;
    }
}

// ---------------------------------------------------------------------------
// K1c: sim pass 2 — 32-step emit from precomputed entry state, two 16-ts
// quarter stages. LDS 8.9 KB.  [r10-verified]
// ---------------------------------------------------------------------------
__global__ __launch_bounds__(64) void sim_pass2(const float* __restrict__ forces,
                                                const float* __restrict__ hmod,
                                                const float* __restrict__ home,
                                                const float* __restrict__ masses,
                                                const float* __restrict__ tensions,
                                                const float* __restrict__ gains,
                                                const float* __restrict__ mics,
                                                const float* __restrict__ w,
                                                float* __restrict__ disp,
                                                float* __restrict__ rec) {
    const int blk = blockIdx.x;
    const int bm = blk >> 6, c = blk & 63;
    const int m = bm & 31;
    const int d = threadIdx.x;
    const int t0 = c * 32;
    __shared__ __align__(16) float ft[64][17];
    __shared__ __align__(16) float ht[64][17];
    const float k = tensions[m * 64 + d] / masses[m];
    const float gain = gains[m];
    const float mic = mics[m * 64 + d];
    const float hd = home[d];

    float pos = w[(size_t)blk * 128 + d];
    float vel = w[(size_t)blk * 128 + 64 + d];

    #pragma unroll
    for (int phase = 0; phase < 2; ++phase) {
        const int t0p = t0 + phase * 16;
        for (int i = d; i < 256; i += 64) {
            const int dd = i >> 2, q = (i & 3) * 4;
            const size_t off = ((size_t)bm * 64 + dd) * 2048 + t0p + q;
            *(float4*)&ft[dd][q] = *(const float4*)(forces + off);
            *(float4*)&ht[dd][q] = *(const float4*)(hmod + off);
        }
        __syncthreads();
        #pragma unroll
        for (int ts = 0; ts < 16; ++ts) {
            const float f = ft[d][ts];
            const float h = hd + ht[d][ts];
            const float dir = h - pos;
            const float acc = f + k * dir;
            vel = (vel + acc) * DAMP;
            pos = pos + vel;
            ft[d][ts] = dir;                        // disp tile (in place)
            const float x = vel * gain;
            const float e = __expf(2.f * x);
            ht[d][ts] = (1.f - 2.f / (e + 1.f)) * mic;   // prod tile (in place)
        }
        __syncthreads();
        for (int i = d; i < 256; i += 64) {
            const int dd = i >> 2, q = (i & 3) * 4;
            const size_t off = ((size_t)bm * 64 + dd) * 2048 + t0p + q;
            *(float4*)(disp + off) = *(float4*)&ft[dd][q];
        }
        {
            const int ts = d & 15, part = d >> 4;
            float s = 0.f;
            #pragma unroll
            for (int j = 0; j < 16; ++j) s += ht[16 * part + j][ts];
            s += __shfl_xor(s, 16);
            s += __shfl_xor(s, 32);
            if (d < 16) rec[(size_t)bm * 2048 + t0p + d] = s;
        }
        __syncthreads();
    }
}

// ---------------------------------------------------------------------------
// K2 (merged): blocks [0,512) = mixture (fp32 acc -> bf16, r9-verified math);
// blocks [512,768) = fft_resample (r14-verified). Independent outputs, both
// depend only on sim outputs -> safe in one dispatch; mix's VALU blocks fill
// SIMDs left idle by resample's 2-block/CU LDS cap.
// ---------------------------------------------------------------------------
#define DR_STRIDE 2064u           // 1024 bf16 + 16B pad; == 16 mod 128
#define W_STRIDE  5136u
#define W_OFF     33024u          // 16*2064
#define RS_SMEM   74112u          // + 8*5136

__global__ __launch_bounds__(256) void mixres_kernel(const float* __restrict__ disp,
                                                     const float* __restrict__ tofm,
                                                     unsigned short* __restrict__ mixture,
                                                     const float* __restrict__ rec,
                                                     const unsigned short* __restrict__ dirrev,
                                                     unsigned short* __restrict__ upb) {
    __shared__ __align__(16) unsigned char smem[RS_SMEM];
    const int tid = threadIdx.x;
    const int blk = blockIdx.x;

    if (blk < 512) {
        // ---- mixture path ----
        float* tf = (float*)smem;            // 64 x 16 f32
        for (int i = tid; i < 1024; i += 256) tf[i] = tofm[i];
        __syncthreads();
        const int bm = blk >> 3;
        const int t = (blk & 7) * 256 + tid;
        float acc[16];
        #pragma unroll
        for (int f = 0; f < 16; ++f) acc[f] = 0.f;
        for (int d = 0; d < 64; ++d) {
            const float v = disp[((size_t)bm * 64 + d) * 2048 + t];
            const float4* r4 = (const float4*)(tf + d * 16);
            const float4 a4 = r4[0], b4 = r4[1], c4 = r4[2], d4 = r4[3];
            acc[0]  += v * a4.x; acc[1]  += v * a4.y; acc[2]  += v * a4.z; acc[3]  += v * a4.w;
            acc[4]  += v * b4.x; acc[5]  += v * b4.y; acc[6]  += v * b4.z; acc[7]  += v * b4.w;
            acc[8]  += v * c4.x; acc[9]  += v * c4.y; acc[10] += v * c4.z; acc[11] += v * c4.w;
            acc[12] += v * d4.x; acc[13] += v * d4.y; acc[14] += v * d4.z; acc[15] += v * d4.w;
        }
        #pragma unroll
        for (int f = 0; f < 16; ++f)
            mixture[((size_t)bm * 16 + f) * 2048 + t] = f2bf(acc[f]);
        return;
    }

    // ---- resample path ----
    const int rblk = blk - 512;
    const int bm = rblk >> 2;
    const int Q0 = (rblk & 3) * 512;

    for (int x = tid; x < 2560; x += 256) {
        const int g = (Q0 + x + 1) & 2047;
        const unsigned short bv = f2bf(rec[(size_t)bm * 2048 + g]);
        #pragma unroll
        for (int sg = 0; sg < 8; ++sg) {
            const int y = x - sg;
            if (y >= 0) *(unsigned short*)(smem + W_OFF + sg * W_STRIDE + 2 * y) = bv;
        }
    }

    const int lane = tid & 63;
    const int wv = tid >> 6;
    const int i15 = lane & 15;
    const int g4 = lane >> 4;

    f32x4 acc[8];
    #pragma unroll
    for (int i = 0; i < 8; ++i) acc[i] = (f32x4){0.f, 0.f, 0.f, 0.f};

    const unsigned abase = (unsigned)i15 * DR_STRIDE + 16u * g4;
    const unsigned bbase = W_OFF + (unsigned)(i15 & 7) * W_STRIDE + 16u * (i15 >> 3) + 16u * g4;

    for (int kc = 0; kc < 2; ++kc) {
        if (kc) __syncthreads();
        for (int i = tid; i < 2048; i += 256) {
            const int p = i >> 7, c16 = i & 127;
            *(uint4*)(smem + (unsigned)p * DR_STRIDE + 16u * c16) =
                *(const uint4*)(dirrev + (size_t)p * 2048 + kc * 1024 + 8 * c16);
        }
        __syncthreads();

        for (int kkb = 0; kkb < 4; ++kkb) {
            bf16x8 afr[8];
            #pragma unroll
            for (int kj = 0; kj < 8; ++kj)
                afr[kj] = *(const bf16x8*)(smem + abase + 64u * (kkb * 8 + kj));
            #pragma unroll
            for (int qtl = 0; qtl < 8; ++qtl) {
                const int qt = wv * 8 + qtl;
                const unsigned bb = bbase + 32u * qt + 2048u * kc;
                #pragma unroll
                for (int kj = 0; kj < 8; ++kj) {
                    const bf16x8 bfr = *(const bf16x8*)(smem + bb + 64u * (kkb * 8 + kj));
                    acc[qtl] = __builtin_amdgcn_mfma_f32_16x16x32_bf16(afr[kj], bfr, acc[qtl], 0, 0, 0);
                }
            }
        }
    }

    #pragma unroll
    for (int qtl = 0; qtl < 8; ++qtl) {
        const int qt = wv * 8 + qtl;
        const int q = Q0 + 16 * qt + i15;
        const int sbase = 16 * q + 4 * g4;
        const unsigned jb = (unsigned)bm * 32768u + (unsigned)sbase;
        u16x4 o;
        o[0] = f2bf(fabsf(acc[qtl][0] * (1.f / 8192.f)) * noise_at(jb));
        o[1] = f2bf(fabsf(acc[qtl][1] * (1.f / 8192.f)) * noise_at(jb + 1u));
        o[2] = f2bf(fabsf(acc[qtl][2] * (1.f / 8192.f)) * noise_at(jb + 2u));
        o[3] = f2bf(fabsf(acc[qtl][3] * (1.f / 8192.f)) * noise_at(jb + 3u));
        *(u16x4*)(upb + (size_t)bm * 32768 + sbase) = o;
    }
}

// ---------------------------------------------------------------------------
// K4 (MFMA): hf — rolling B-fragment buffer + 2-way accumulator split
// (even kk -> acc0, odd kk -> acc1) to break the 16-deep MFMA dependency
// chain. Addresses identical to r10-verified version.
// grid (32 s-tiles of 1024, 64 bm), 256 threads.
// ---------------------------------------------------------------------------
#define W_STR2   3088u            // 1544 bf16, padded (1536 used)
#define MX_OFF   24704u           // 8*3088
#define HF_SMEM  26880u           // + 16*68*2

__global__ __launch_bounds__(256) void hf_kernel(const unsigned short* __restrict__ upb,
                                                 const unsigned short* __restrict__ fnrev,
                                                 const unsigned short* __restrict__ mixture,
                                                 float* __restrict__ hf) {
    const int tile = blockIdx.x;     // 0..31
    const int bm = blockIdx.y;       // 0..63
    const int b = bm >> 5;
    const int S0 = tile * 1024;
    const int tbase = tile * 64 - 1;
    const int tid = threadIdx.x;

    __shared__ __align__(16) unsigned char smem[HF_SMEM];
    unsigned short* mixl = (unsigned short*)(smem + MX_OFF);

    // stage 8 shifted copies: W[x] = upb[S0-511+x], x in [0,1536)
    for (int x = tid; x < 1536; x += 256) {
        const int gidx = S0 - 511 + x;
        const unsigned short v = (gidx >= 0) ? upb[(size_t)bm * 32768 + gidx]
                                             : (unsigned short)0;
        #pragma unroll
        for (int sg = 0; sg < 8; ++sg) {
            const int y = x - sg;
            if (y >= 0) *(unsigned short*)(smem + sg * W_STR2 + 2 * y) = v;
        }
    }
    // stage mixl window (bf16): 16 f x 66 t
    for (int i = tid; i < 16 * 66; i += 256) {
        const int f = i / 66, tt = i - f * 66;
        const int t = tbase + tt;
        mixl[f * 68 + tt] = (t >= 0 && t < 2048)
            ? mixture[((size_t)bm * 16 + f) * 2048 + t] : (unsigned short)0;
    }
    // A-fragments from fnrev (L2-cached, 16B aligned loads)
    const int lane = tid & 63;
    const int i15 = lane & 15;
    const int g4 = lane >> 4;
    const int wv = tid >> 6;
    bf16x8 afr[16];
    #pragma unroll
    for (int kk = 0; kk < 16; ++kk)
        afr[kk] = *(const bf16x8*)(fnrev + (size_t)(b * 16 + i15) * 512 + 32 * kk + 8 * g4);
    __syncthreads();

    for (int rr = 0; rr < 4; ++rr) {
        const int rho = wv * 4 + rr;            // s residue 0..15
        const int sig = rho & 7;
        const unsigned baseR = (unsigned)sig * W_STR2 + 2u * (rho - sig)
                             + 32u * i15 + 16u * g4;
        // rolling window fragment buffer: frag j lives in slot j & 15
        bf16x8 wfr[16];
        #pragma unroll
        for (int j = 0; j < 8; ++j)
            wfr[j] = *(const bf16x8*)(smem + baseR + 64u * j);
        #pragma unroll
        for (int g = 0; g < 4; ++g) {
            #pragma unroll
            for (int jj = 0; jj < 8; ++jj) {
                const int j = 8 * g + 8 + jj;
                wfr[j & 15] = *(const bf16x8*)(smem + baseR + 64u * (unsigned)j);
            }
            f32x4 acc0 = {0.f, 0.f, 0.f, 0.f};
            f32x4 acc1 = {0.f, 0.f, 0.f, 0.f};
            #pragma unroll
            for (int kk = 0; kk < 16; kk += 2) {
                acc0 = __builtin_amdgcn_mfma_f32_16x16x32_bf16(afr[kk], wfr[(8 * g + kk) & 15], acc0, 0, 0, 0);
                acc1 = __builtin_amdgcn_mfma_f32_16x16x32_bf16(afr[kk + 1], wfr[(8 * g + kk + 1) & 15], acc1, 0, 0, 0);
            }
            const f32x4 acc = acc0 + acc1;
            const int s = S0 + 256 * g + rho + 16 * i15;
            float posf = ((float)s + 0.5f) * 0.0625f - 0.5f;
            posf = fminf(fmaxf(posf, 0.f), 2047.f);
            const int i0 = (int)posf;
            const float wg = posf - (float)i0;
            const int i1 = min(i0 + 1, 2047);
            const int t0 = i0 - tbase, t1 = i1 - tbase;
            float part = 0.f;
            #pragma unroll
            for (int r = 0; r < 4; ++r) {
                const int f = 4 * g4 + r;
                const float mv = bf2f(mixl[f * 68 + t0]) * (1.f - wg)
                               + bf2f(mixl[f * 68 + t1]) * wg;
                part += mv * acc[r];
            }
            part += __shfl_xor(part, 16);
            part += __shfl_xor(part, 32);
            if (g4 == 0) {
                const int e = 511 + 256 * g + rho + 16 * i15;   // copy-0 element
                const float upv = bf2f(*(const unsigned short*)(smem + 2 * e));
                hf[(size_t)bm * 32768 + s] = part + upv;
            }
        }
    }
}

// ---------------------------------------------------------------------------
// Launch
// ---------------------------------------------------------------------------
extern "C" void kernel_launch(void* const* d_in, const int* in_sizes, int n_in,
                              void* d_out, int out_size, void* d_ws, size_t ws_size,
                              hipStream_t stream) {
    const float* forces   = (const float*)d_in[0];
    const float* hmod     = (const float*)d_in[1];
    const float* filters  = (const float*)d_in[2];
    const float* home     = (const float*)d_in[3];
    const float* masses   = (const float*)d_in[4];
    const float* tensions = (const float*)d_in[5];
    const float* gains    = (const float*)d_in[6];
    const float* mics     = (const float*)d_in[7];
    const float* tofm     = (const float*)d_in[8];

    float* out  = (float*)d_out;
    float* rec  = out;                  // 131072
    float* disp = out + 131072;         // 8388608
    float* hf   = out + 8519680;        // 2097152

    unsigned short* upb     = (unsigned short*)d_ws;                    // 2097152 bf16 (4MB)
    unsigned short* mixture = (unsigned short*)((float*)d_ws + 1048576);// 2097152 bf16 (4MB)
    unsigned short* dirrev  = (unsigned short*)((float*)d_ws + 2097152);// 32768 bf16
    float* w                = (float*)d_ws + 2113536;                   // 524288 f32 (2MB)
    unsigned short* fnrev   = (unsigned short*)((float*)d_ws + 2637824);// 16384 bf16
    // total ws use ~10.2 MB

    sim_pass1<<<4640, 64, 0, stream>>>(forces, hmod, home, masses, tensions, w,
                                       filters, dirrev, fnrev);
    sim_scan<<<64, 64, 0, stream>>>(masses, tensions, w);
    sim_pass2<<<4096, 64, 0, stream>>>(forces, hmod, home, masses, tensions, gains, mics, w, disp, rec);
    mixres_kernel<<<768, 256, 0, stream>>>(disp, tofm, mixture, rec, dirrev, upb);
    hf_kernel<<<dim3(32, 64), 256, 0, stream>>>(upb, fnrev, mixture, hf);
}

// Round 17
// 125.623 us; speedup vs baseline: 1.0468x; 1.0468x over previous
//
#include <hip/hip_runtime.h>
#include <cstdint>
#include <cstddef>

// Problem constants (B=2, M=32, D=64, T=2048, F=16, L=512, S=32768)
#define DAMP 0.9998f

typedef __attribute__((ext_vector_type(8))) short bf16x8;
typedef __attribute__((ext_vector_type(4))) unsigned short u16x4;
typedef __attribute__((ext_vector_type(4))) float f32x4;

__device__ __forceinline__ unsigned short f2bf(float x) {
    unsigned u = __float_as_uint(x);
    unsigned r = (u + 0x7FFFu + ((u >> 16) & 1u)) >> 16;   // RNE
    return (unsigned short)r;
}
__device__ __forceinline__ float bf2f(unsigned short v) {
    return __uint_as_float((unsigned)v << 16);
}

// ---------------------------------------------------------------------------
// threefry2x32, JAX partitionable mode. key=(0,1); counter (0, j); o0^o1.
// [verified r4]
// ---------------------------------------------------------------------------
__device__ __forceinline__ void threefry_0j(unsigned j, unsigned& o0, unsigned& o1) {
    unsigned x0 = 0u;
    unsigned x1 = j + 1u;
    const unsigned ks2 = 0x1BD11BDBu;
#define TFR(r) { x0 += x1; x1 = (x1 << (r)) | (x1 >> (32 - (r))); x1 ^= x0; }
    TFR(13) TFR(15) TFR(26) TFR(6)
    x0 += 1u;   x1 += ks2 + 1u;
    TFR(17) TFR(29) TFR(16) TFR(24)
    x0 += ks2;  x1 += 0u + 2u;
    TFR(13) TFR(15) TFR(26) TFR(6)
    /*x0+=0*/   x1 += 1u + 3u;
    TFR(17) TFR(29) TFR(16) TFR(24)
    x0 += 1u;   x1 += ks2 + 4u;
    TFR(13) TFR(15) TFR(26) TFR(6)
    x0 += ks2;  x1 += 0u + 5u;
#undef TFR
    o0 = x0; o1 = x1;
}

__device__ __forceinline__ float noise_at(unsigned j) {
    unsigned o0, o1;
    threefry_0j(j, o0, o1);
    unsigned bits = o0 ^ o1;
    float u = __uint_as_float((bits >> 9) | 0x3F800000u) - 1.0f;
    return fmaxf(-1.0f, u * 2.0f - 1.0f);
}

// Dir(u) = sin(2049*pi*u/32768)/sin(pi*u/32768), Dir(0)=2049, period 32768.
__device__ __forceinline__ float dir_val(unsigned u) {
    if (u == 0u) return 2049.f;
    const float PIO = 9.58737992e-05f;
    unsigned y = (2049u * u) & 65535u;
    float sgn = 1.f;
    if (y >= 32768u) { y -= 32768u; sgn = -1.f; }
    unsigned yy = (y > 16384u) ? (32768u - y) : y;
    float sy = sgn * sinf((float)yy * PIO);
    unsigned uu = (u > 16384u) ? (32768u - u) : u;
    float su = sinf((float)uu * PIO);
    return sy / su;
}

// ---------------------------------------------------------------------------
// K1a: sim pass 1 + tables. Blocks [0,4096): 32-step chunk local affine
// constant w_c (r10-verified). Blocks [4096,4608): DirRev table. Blocks
// [4608,4640): normalized reversed filters.
// ---------------------------------------------------------------------------
__global__ __launch_bounds__(64) void sim_pass1(const float* __restrict__ forces,
                                                const float* __restrict__ hmod,
                                                const float* __restrict__ home,
                                                const float* __restrict__ masses,
                                                const float* __restrict__ tensions,
                                                float* __restrict__ w,
                                                const float* __restrict__ filters,
                                                unsigned short* __restrict__ dirrev,
                                                unsigned short* __restrict__ fnrev) {
    const int blk = blockIdx.x;
    const int d = threadIdx.x;
    if (blk >= 4608) {               // fnrev: 32 blocks x 64 threads
        const int row = blk - 4608;
        const float* src = filters + (size_t)row * 512;
        float s = 0.f;
        for (int i = d; i < 512; i += 64) { const float v = src[i]; s += v * v; }
        #pragma unroll
        for (int off = 32; off; off >>= 1) s += __shfl_xor(s, off);
        const float scale = 1.f / (sqrtf(s) + 1e-8f);
        for (int i = d; i < 512; i += 64)
            fnrev[(size_t)row * 512 + i] = f2bf(src[511 - i] * scale);
        return;
    }
    if (blk >= 4096) {               // dirrev: 512 blocks x 64 threads
        const unsigned i = (unsigned)(blk - 4096) * 64u + (unsigned)d;
        const unsigned p = i >> 11, k = i & 2047u;
        dirrev[i] = f2bf(dir_val(16u * (2047u - k) + p));
        return;
    }
    const int bm = blk >> 6, c = blk & 63;
    const int m = bm & 31;
    const int t0 = c * 32;
    __shared__ float kv[64];
    __shared__ float hv[64];
    __shared__ __align__(16) float gt[64][33];
    kv[d] = tensions[m * 64 + d] / masses[m];
    hv[d] = home[d];
    __syncthreads();
    for (int i = d; i < 512; i += 64) {
        const int dd = i >> 3, q = (i & 7) * 4;
        const size_t off = ((size_t)bm * 64 + dd) * 2048 + t0 + q;
        const float4 fv = *(const float4*)(forces + off);
        const float4 hm = *(const float4*)(hmod + off);
        const float kk = kv[dd], hh = hv[dd];
        float4 g;
        g.x = fmaf(kk, hh + hm.x, fv.x);
        g.y = fmaf(kk, hh + hm.y, fv.y);
        g.z = fmaf(kk, hh + hm.z, fv.z);
        g.w = fmaf(kk, hh + hm.w, fv.w);
        *(float4*)&gt[dd][q] = g;
    }
    __syncthreads();
    const float k = kv[d];
    float pos = 0.f, vel = 0.f;
    #pragma unroll 8
    for (int ts = 0; ts < 32; ++ts) {
        const float acc = fmaf(-k, pos, gt[d][ts]);
        vel = (vel + acc) * DAMP;
        pos = pos + vel;
    }
    float* wrow = w + (size_t)blk * 128;
    wrow[d] = pos; wrow[64 + d] = vel;
}

// ---------------------------------------------------------------------------
// K1b: sim scan — fp64 A^32, serial scan over 64 chunks per (bm,d).
// LDS-staged: the whole 32KB w-block is loaded cooperatively into LDS first
// (parallel, coalesced), breaking the load->store->load aliasing chain of the
// old in-place version; the serial scan then runs register/LDS-local with
// fire-and-forget global stores. grid 64 (bm), 64 threads (d).
// ---------------------------------------------------------------------------
__global__ __launch_bounds__(64) void sim_scan(const float* __restrict__ masses,
                                               const float* __restrict__ tensions,
                                               float* __restrict__ w) {
    const int bm = blockIdx.x;
    const int m = bm & 31;
    const int d = threadIdx.x;
    __shared__ __align__(16) float wl[8192];     // 64 chunks x 128 f32 = 32 KB

    float* wb = w + (size_t)bm * 64 * 128;
    const float4* w4 = (const float4*)wb;
    float4* wl4 = (float4*)wl;
    for (int i = d; i < 2048; i += 64) wl4[i] = w4[i];   // parallel stage

    const double kd = (double)(tensions[m * 64 + d] / masses[m]);
    const double cd = (double)DAMP;
    double Ma = 1.0 - cd * kd, Mb = cd, Mc = -cd * kd, Md = cd;
    #pragma unroll
    for (int it = 0; it < 5; ++it) {             // A^(2^5) = A^32
        const double na = Ma * Ma + Mb * Mc;
        const double nb = Ma * Mb + Mb * Md;
        const double nc = Mc * Ma + Md * Mc;
        const double nd = Mc * Mb + Md * Md;
        Ma = na; Mb = nb; Mc = nc; Md = nd;
    }
    __syncthreads();
    double pos = 0.0, vel = 0.0;
    for (int c = 0; c < 64; ++c) {
        const double wp = (double)wl[c * 128 + d];
        const double wv = (double)wl[c * 128 + 64 + d];
        wb[c * 128 + d] = (float)pos;            // entry state of chunk c
        wb[c * 128 + 64 + d] = (float)vel;
        const double np = Ma * pos + Mb * vel + wp;
        const double nv = Mc * pos + Md * vel + wv;
        pos = np; vel = nv;
    }
}

// ---------------------------------------------------------------------------
// K1c: sim pass 2 — 32-step emit from precomputed entry state, two 16-ts
// quarter stages. LDS 8.9 KB.  [r10-verified]
// ---------------------------------------------------------------------------
__global__ __launch_bounds__(64) void sim_pass2(const float* __restrict__ forces,
                                                const float* __restrict__ hmod,
                                                const float* __restrict__ home,
                                                const float* __restrict__ masses,
                                                const float* __restrict__ tensions,
                                                const float* __restrict__ gains,
                                                const float* __restrict__ mics,
                                                const float* __restrict__ w,
                                                float* __restrict__ disp,
                                                float* __restrict__ rec) {
    const int blk = blockIdx.x;
    const int bm = blk >> 6, c = blk & 63;
    const int m = bm & 31;
    const int d = threadIdx.x;
    const int t0 = c * 32;
    __shared__ __align__(16) float ft[64][17];
    __shared__ __align__(16) float ht[64][17];
    const float k = tensions[m * 64 + d] / masses[m];
    const float gain = gains[m];
    const float mic = mics[m * 64 + d];
    const float hd = home[d];

    float pos = w[(size_t)blk * 128 + d];
    float vel = w[(size_t)blk * 128 + 64 + d];

    #pragma unroll
    for (int phase = 0; phase < 2; ++phase) {
        const int t0p = t0 + phase * 16;
        for (int i = d; i < 256; i += 64) {
            const int dd = i >> 2, q = (i & 3) * 4;
            const size_t off = ((size_t)bm * 64 + dd) * 2048 + t0p + q;
            *(float4*)&ft[dd][q] = *(const float4*)(forces + off);
            *(float4*)&ht[dd][q] = *(const float4*)(hmod + off);
        }
        __syncthreads();
        #pragma unroll
        for (int ts = 0; ts < 16; ++ts) {
            const float f = ft[d][ts];
            const float h = hd + ht[d][ts];
            const float dir = h - pos;
            const float acc = f + k * dir;
            vel = (vel + acc) * DAMP;
            pos = pos + vel;
            ft[d][ts] = dir;                        // disp tile (in place)
            const float x = vel * gain;
            const float e = __expf(2.f * x);
            ht[d][ts] = (1.f - 2.f / (e + 1.f)) * mic;   // prod tile (in place)
        }
        __syncthreads();
        for (int i = d; i < 256; i += 64) {
            const int dd = i >> 2, q = (i & 3) * 4;
            const size_t off = ((size_t)bm * 64 + dd) * 2048 + t0p + q;
            *(float4*)(disp + off) = *(float4*)&ft[dd][q];
        }
        {
            const int ts = d & 15, part = d >> 4;
            float s = 0.f;
            #pragma unroll
            for (int j = 0; j < 16; ++j) s += ht[16 * part + j][ts];
            s += __shfl_xor(s, 16);
            s += __shfl_xor(s, 32);
            if (d < 16) rec[(size_t)bm * 2048 + t0p + d] = s;
        }
        __syncthreads();
    }
}

// ---------------------------------------------------------------------------
// K2: mixture (fp32 acc -> bf16). [r9-verified, standalone again]
// ---------------------------------------------------------------------------
__global__ __launch_bounds__(256) void mix_kernel(const float* __restrict__ disp,
                                                  const float* __restrict__ tofm,
                                                  unsigned short* __restrict__ mixture) {
    __shared__ __align__(16) float tf[64][16];
    const int tid = threadIdx.x;
    for (int i = tid; i < 1024; i += 256) tf[i >> 4][i & 15] = tofm[i];
    __syncthreads();
    const int bm = blockIdx.y;
    const int t = blockIdx.x * 256 + tid;
    float acc[16];
    #pragma unroll
    for (int f = 0; f < 16; ++f) acc[f] = 0.f;
    for (int d = 0; d < 64; ++d) {
        const float v = disp[((size_t)bm * 64 + d) * 2048 + t];
        const float4* r4 = (const float4*)tf[d];
        const float4 a4 = r4[0], b4 = r4[1], c4 = r4[2], d4 = r4[3];
        acc[0]  += v * a4.x; acc[1]  += v * a4.y; acc[2]  += v * a4.z; acc[3]  += v * a4.w;
        acc[4]  += v * b4.x; acc[5]  += v * b4.y; acc[6]  += v * b4.z; acc[7]  += v * b4.w;
        acc[8]  += v * c4.x; acc[9]  += v * c4.y; acc[10] += v * c4.z; acc[11] += v * c4.w;
        acc[12] += v * d4.x; acc[13] += v * d4.y; acc[14] += v * d4.z; acc[15] += v * d4.w;
    }
    #pragma unroll
    for (int f = 0; f < 16; ++f)
        mixture[((size_t)bm * 16 + f) * 2048 + t] = f2bf(acc[f]);
}

// ---------------------------------------------------------------------------
// K3 (MFMA): fft_resample — 2-chunk DirRev staging, bf16 up output.
// [unchanged r14]
// ---------------------------------------------------------------------------
#define DR_STRIDE 2064u           // 1024 bf16 + 16B pad; == 16 mod 128
#define W_STRIDE  5136u
#define W_OFF     33024u          // 16*2064
#define RS_SMEM   74112u          // + 8*5136

__global__ __launch_bounds__(256) void resample_kernel(const float* __restrict__ rec,
                                                       const unsigned short* __restrict__ dirrev,
                                                       unsigned short* __restrict__ upb) {
    const int bm = blockIdx.x;
    const int Q0 = blockIdx.y * 512;
    const int tid = threadIdx.x;
    __shared__ __align__(16) unsigned char smem[RS_SMEM];

    for (int x = tid; x < 2560; x += 256) {
        const int g = (Q0 + x + 1) & 2047;
        const unsigned short bv = f2bf(rec[(size_t)bm * 2048 + g]);
        #pragma unroll
        for (int sg = 0; sg < 8; ++sg) {
            const int y = x - sg;
            if (y >= 0) *(unsigned short*)(smem + W_OFF + sg * W_STRIDE + 2 * y) = bv;
        }
    }

    const int lane = tid & 63;
    const int wv = tid >> 6;
    const int i15 = lane & 15;
    const int g4 = lane >> 4;

    f32x4 acc[8];
    #pragma unroll
    for (int i = 0; i < 8; ++i) acc[i] = (f32x4){0.f, 0.f, 0.f, 0.f};

    const unsigned abase = (unsigned)i15 * DR_STRIDE + 16u * g4;
    const unsigned bbase = W_OFF + (unsigned)(i15 & 7) * W_STRIDE + 16u * (i15 >> 3) + 16u * g4;

    for (int kc = 0; kc < 2; ++kc) {
        if (kc) __syncthreads();
        for (int i = tid; i < 2048; i += 256) {
            const int p = i >> 7, c16 = i & 127;
            *(uint4*)(smem + (unsigned)p * DR_STRIDE + 16u * c16) =
                *(const uint4*)(dirrev + (size_t)p * 2048 + kc * 1024 + 8 * c16);
        }
        __syncthreads();

        for (int kkb = 0; kkb < 4; ++kkb) {
            bf16x8 afr[8];
            #pragma unroll
            for (int kj = 0; kj < 8; ++kj)
                afr[kj] = *(const bf16x8*)(smem + abase + 64u * (kkb * 8 + kj));
            #pragma unroll
            for (int qtl = 0; qtl < 8; ++qtl) {
                const int qt = wv * 8 + qtl;
                const unsigned bb = bbase + 32u * qt + 2048u * kc;
                #pragma unroll
                for (int kj = 0; kj < 8; ++kj) {
                    const bf16x8 bfr = *(const bf16x8*)(smem + bb + 64u * (kkb * 8 + kj));
                    acc[qtl] = __builtin_amdgcn_mfma_f32_16x16x32_bf16(afr[kj], bfr, acc[qtl], 0, 0, 0);
                }
            }
        }
    }

    #pragma unroll
    for (int qtl = 0; qtl < 8; ++qtl) {
        const int qt = wv * 8 + qtl;
        const int q = Q0 + 16 * qt + i15;
        const int sbase = 16 * q + 4 * g4;
        const unsigned jb = (unsigned)bm * 32768u + (unsigned)sbase;
        u16x4 o;
        o[0] = f2bf(fabsf(acc[qtl][0] * (1.f / 8192.f)) * noise_at(jb));
        o[1] = f2bf(fabsf(acc[qtl][1] * (1.f / 8192.f)) * noise_at(jb + 1u));
        o[2] = f2bf(fabsf(acc[qtl][2] * (1.f / 8192.f)) * noise_at(jb + 2u));
        o[3] = f2bf(fabsf(acc[qtl][3] * (1.f / 8192.f)) * noise_at(jb + 3u));
        *(u16x4*)(upb + (size_t)bm * 32768 + sbase) = o;
    }
}

// ---------------------------------------------------------------------------
// K4 (MFMA): hf — rolling B-fragment buffer, single 16-deep accumulator
// (r15-verified: VGPR=64, exactly at the occupancy boundary — do not grow).
// grid (32 s-tiles of 1024, 64 bm), 256 threads.
// ---------------------------------------------------------------------------
#define W_STR2   3088u            // 1544 bf16, padded (1536 used)
#define MX_OFF   24704u           // 8*3088
#define HF_SMEM  26880u           // + 16*68*2

__global__ __launch_bounds__(256) void hf_kernel(const unsigned short* __restrict__ upb,
                                                 const unsigned short* __restrict__ fnrev,
                                                 const unsigned short* __restrict__ mixture,
                                                 float* __restrict__ hf) {
    const int tile = blockIdx.x;     // 0..31
    const int bm = blockIdx.y;       // 0..63
    const int b = bm >> 5;
    const int S0 = tile * 1024;
    const int tbase = tile * 64 - 1;
    const int tid = threadIdx.x;

    __shared__ __align__(16) unsigned char smem[HF_SMEM];
    unsigned short* mixl = (unsigned short*)(smem + MX_OFF);

    // stage 8 shifted copies: W[x] = upb[S0-511+x], x in [0,1536)
    for (int x = tid; x < 1536; x += 256) {
        const int gidx = S0 - 511 + x;
        const unsigned short v = (gidx >= 0) ? upb[(size_t)bm * 32768 + gidx]
                                             : (unsigned short)0;
        #pragma unroll
        for (int sg = 0; sg < 8; ++sg) {
            const int y = x - sg;
            if (y >= 0) *(unsigned short*)(smem + sg * W_STR2 + 2 * y) = v;
        }
    }
    // stage mixl window (bf16): 16 f x 66 t
    for (int i = tid; i < 16 * 66; i += 256) {
        const int f = i / 66, tt = i - f * 66;
        const int t = tbase + tt;
        mixl[f * 68 + tt] = (t >= 0 && t < 2048)
            ? mixture[((size_t)bm * 16 + f) * 2048 + t] : (unsigned short)0;
    }
    // A-fragments from fnrev (L2-cached, 16B aligned loads)
    const int lane = tid & 63;
    const int i15 = lane & 15;
    const int g4 = lane >> 4;
    const int wv = tid >> 6;
    bf16x8 afr[16];
    #pragma unroll
    for (int kk = 0; kk < 16; ++kk)
        afr[kk] = *(const bf16x8*)(fnrev + (size_t)(b * 16 + i15) * 512 + 32 * kk + 8 * g4);
    __syncthreads();

    for (int rr = 0; rr < 4; ++rr) {
        const int rho = wv * 4 + rr;            // s residue 0..15
        const int sig = rho & 7;
        const unsigned baseR = (unsigned)sig * W_STR2 + 2u * (rho - sig)
                             + 32u * i15 + 16u * g4;
        // rolling window fragment buffer: frag j lives in slot j & 15
        bf16x8 wfr[16];
        #pragma unroll
        for (int j = 0; j < 8; ++j)
            wfr[j] = *(const bf16x8*)(smem + baseR + 64u * j);
        #pragma unroll
        for (int g = 0; g < 4; ++g) {
            #pragma unroll
            for (int jj = 0; jj < 8; ++jj) {
                const int j = 8 * g + 8 + jj;
                wfr[j & 15] = *(const bf16x8*)(smem + baseR + 64u * (unsigned)j);
            }
            f32x4 acc = {0.f, 0.f, 0.f, 0.f};
            #pragma unroll
            for (int kk = 0; kk < 16; ++kk)
                acc = __builtin_amdgcn_mfma_f32_16x16x32_bf16(afr[kk], wfr[(8 * g + kk) & 15], acc, 0, 0, 0);
            const int s = S0 + 256 * g + rho + 16 * i15;
            float posf = ((float)s + 0.5f) * 0.0625f - 0.5f;
            posf = fminf(fmaxf(posf, 0.f), 2047.f);
            const int i0 = (int)posf;
            const float wg = posf - (float)i0;
            const int i1 = min(i0 + 1, 2047);
            const int t0 = i0 - tbase, t1 = i1 - tbase;
            float part = 0.f;
            #pragma unroll
            for (int r = 0; r < 4; ++r) {
                const int f = 4 * g4 + r;
                const float mv = bf2f(mixl[f * 68 + t0]) * (1.f - wg)
                               + bf2f(mixl[f * 68 + t1]) * wg;
                part += mv * acc[r];
            }
            part += __shfl_xor(part, 16);
            part += __shfl_xor(part, 32);
            if (g4 == 0) {
                const int e = 511 + 256 * g + rho + 16 * i15;   // copy-0 element
                const float upv = bf2f(*(const unsigned short*)(smem + 2 * e));
                hf[(size_t)bm * 32768 + s] = part + upv;
            }
        }
    }
}

// ---------------------------------------------------------------------------
// Launch
// ---------------------------------------------------------------------------
extern "C" void kernel_launch(void* const* d_in, const int* in_sizes, int n_in,
                              void* d_out, int out_size, void* d_ws, size_t ws_size,
                              hipStream_t stream) {
    const float* forces   = (const float*)d_in[0];
    const float* hmod     = (const float*)d_in[1];
    const float* filters  = (const float*)d_in[2];
    const float* home     = (const float*)d_in[3];
    const float* masses   = (const float*)d_in[4];
    const float* tensions = (const float*)d_in[5];
    const float* gains    = (const float*)d_in[6];
    const float* mics     = (const float*)d_in[7];
    const float* tofm     = (const float*)d_in[8];

    float* out  = (float*)d_out;
    float* rec  = out;                  // 131072
    float* disp = out + 131072;         // 8388608
    float* hf   = out + 8519680;        // 2097152

    unsigned short* upb     = (unsigned short*)d_ws;                    // 2097152 bf16 (4MB)
    unsigned short* mixture = (unsigned short*)((float*)d_ws + 1048576);// 2097152 bf16 (4MB)
    unsigned short* dirrev  = (unsigned short*)((float*)d_ws + 2097152);// 32768 bf16
    float* w                = (float*)d_ws + 2113536;                   // 524288 f32 (2MB)
    unsigned short* fnrev   = (unsigned short*)((float*)d_ws + 2637824);// 16384 bf16
    // total ws use ~10.2 MB

    sim_pass1<<<4640, 64, 0, stream>>>(forces, hmod, home, masses, tensions, w,
                                       filters, dirrev, fnrev);
    sim_scan<<<64, 64, 0, stream>>>(masses, tensions, w);
    sim_pass2<<<4096, 64, 0, stream>>>(forces, hmod, home, masses, tensions, gains, mics, w, disp, rec);
    mix_kernel<<<dim3(8, 64), 256, 0, stream>>>(disp, tofm, mixture);
    resample_kernel<<<dim3(64, 4), 256, 0, stream>>>(rec, dirrev, upb);
    hf_kernel<<<dim3(32, 64), 256, 0, stream>>>(upb, fnrev, mixture, hf);
}

// Round 18
// 119.482 us; speedup vs baseline: 1.1006x; 1.0514x over previous
//
#include <hip/hip_runtime.h>
#include <cstdint>
#include <cstddef>

// Problem constants (B=2, M=32, D=64, T=2048, F=16, L=512, S=32768)
#define DAMP 0.9998f

typedef __attribute__((ext_vector_type(8))) short bf16x8;
typedef __attribute__((ext_vector_type(4))) unsigned short u16x4;
typedef __attribute__((ext_vector_type(4))) float f32x4;

__device__ __forceinline__ unsigned short f2bf(float x) {
    unsigned u = __float_as_uint(x);
    unsigned r = (u + 0x7FFFu + ((u >> 16) & 1u)) >> 16;   // RNE
    return (unsigned short)r;
}
__device__ __forceinline__ float bf2f(unsigned short v) {
    return __uint_as_float((unsigned)v << 16);
}

// ---------------------------------------------------------------------------
// threefry2x32, JAX partitionable mode. key=(0,1); counter (0, j); o0^o1.
// [verified r4]
// ---------------------------------------------------------------------------
__device__ __forceinline__ void threefry_0j(unsigned j, unsigned& o0, unsigned& o1) {
    unsigned x0 = 0u;
    unsigned x1 = j + 1u;
    const unsigned ks2 = 0x1BD11BDBu;
#define TFR(r) { x0 += x1; x1 = (x1 << (r)) | (x1 >> (32 - (r))); x1 ^= x0; }
    TFR(13) TFR(15) TFR(26) TFR(6)
    x0 += 1u;   x1 += ks2 + 1u;
    TFR(17) TFR(29) TFR(16) TFR(24)
    x0 += ks2;  x1 += 0u + 2u;
    TFR(13) TFR(15) TFR(26) TFR(6)
    /*x0+=0*/   x1 += 1u + 3u;
    TFR(17) TFR(29) TFR(16) TFR(24)
    x0 += 1u;   x1 += ks2 + 4u;
    TFR(13) TFR(15) TFR(26) TFR(6)
    x0 += ks2;  x1 += 0u + 5u;
#undef TFR
    o0 = x0; o1 = x1;
}

__device__ __forceinline__ float noise_at(unsigned j) {
    unsigned o0, o1;
    threefry_0j(j, o0, o1);
    unsigned bits = o0 ^ o1;
    float u = __uint_as_float((bits >> 9) | 0x3F800000u) - 1.0f;
    return fmaxf(-1.0f, u * 2.0f - 1.0f);
}

// Dir(u) = sin(2049*pi*u/32768)/sin(pi*u/32768), Dir(0)=2049, period 32768.
__device__ __forceinline__ float dir_val(unsigned u) {
    if (u == 0u) return 2049.f;
    const float PIO = 9.58737992e-05f;
    unsigned y = (2049u * u) & 65535u;
    float sgn = 1.f;
    if (y >= 32768u) { y -= 32768u; sgn = -1.f; }
    unsigned yy = (y > 16384u) ? (32768u - y) : y;
    float sy = sgn * sinf((float)yy * PIO);
    unsigned uu = (u > 16384u) ? (32768u - u) : u;
    float su = sinf((float)uu * PIO);
    return sy / su;
}

// ---------------------------------------------------------------------------
// K1a: sim pass 1 + tables. Blocks [0,4096): 32-step chunk local affine
// constant w_c (r10-verified). Blocks [4096,4608): DirRev table. Blocks
// [4608,4640): normalized reversed filters.
// ---------------------------------------------------------------------------
__global__ __launch_bounds__(64) void sim_pass1(const float* __restrict__ forces,
                                                const float* __restrict__ hmod,
                                                const float* __restrict__ home,
                                                const float* __restrict__ masses,
                                                const float* __restrict__ tensions,
                                                float* __restrict__ w,
                                                const float* __restrict__ filters,
                                                unsigned short* __restrict__ dirrev,
                                                unsigned short* __restrict__ fnrev) {
    const int blk = blockIdx.x;
    const int d = threadIdx.x;
    if (blk >= 4608) {               // fnrev: 32 blocks x 64 threads
        const int row = blk - 4608;
        const float* src = filters + (size_t)row * 512;
        float s = 0.f;
        for (int i = d; i < 512; i += 64) { const float v = src[i]; s += v * v; }
        #pragma unroll
        for (int off = 32; off; off >>= 1) s += __shfl_xor(s, off);
        const float scale = 1.f / (sqrtf(s) + 1e-8f);
        for (int i = d; i < 512; i += 64)
            fnrev[(size_t)row * 512 + i] = f2bf(src[511 - i] * scale);
        return;
    }
    if (blk >= 4096) {               // dirrev: 512 blocks x 64 threads
        const unsigned i = (unsigned)(blk - 4096) * 64u + (unsigned)d;
        const unsigned p = i >> 11, k = i & 2047u;
        dirrev[i] = f2bf(dir_val(16u * (2047u - k) + p));
        return;
    }
    const int bm = blk >> 6, c = blk & 63;
    const int m = bm & 31;
    const int t0 = c * 32;
    __shared__ float kv[64];
    __shared__ float hv[64];
    __shared__ __align__(16) float gt[64][33];
    kv[d] = tensions[m * 64 + d] / masses[m];
    hv[d] = home[d];
    __syncthreads();
    for (int i = d; i < 512; i += 64) {
        const int dd = i >> 3, q = (i & 7) * 4;
        const size_t off = ((size_t)bm * 64 + dd) * 2048 + t0 + q;
        const float4 fv = *(const float4*)(forces + off);
        const float4 hm = *(const float4*)(hmod + off);
        const float kk = kv[dd], hh = hv[dd];
        float4 g;
        g.x = fmaf(kk, hh + hm.x, fv.x);
        g.y = fmaf(kk, hh + hm.y, fv.y);
        g.z = fmaf(kk, hh + hm.z, fv.z);
        g.w = fmaf(kk, hh + hm.w, fv.w);
        *(float4*)&gt[dd][q] = g;
    }
    __syncthreads();
    const float k = kv[d];
    float pos = 0.f, vel = 0.f;
    #pragma unroll 8
    for (int ts = 0; ts < 32; ++ts) {
        const float acc = fmaf(-k, pos, gt[d][ts]);
        vel = (vel + acc) * DAMP;
        pos = pos + vel;
    }
    float* wrow = w + (size_t)blk * 128;
    wrow[d] = pos; wrow[64 + d] = vel;
}

// ---------------------------------------------------------------------------
// K1b: sim scan — fp64 A^32, serial scan over 64 chunks per (bm,d).
// IN PLACE.  grid 64 (bm), 64 threads (d).  [r10/r15-verified — the r17
// LDS-staged variant regressed; reverted]
// ---------------------------------------------------------------------------
__global__ __launch_bounds__(64) void sim_scan(const float* __restrict__ masses,
                                               const float* __restrict__ tensions,
                                               float* __restrict__ w) {
    const int bm = blockIdx.x;
    const int m = bm & 31;
    const int d = threadIdx.x;
    const double kd = (double)(tensions[m * 64 + d] / masses[m]);
    const double cd = (double)DAMP;
    double Ma = 1.0 - cd * kd, Mb = cd, Mc = -cd * kd, Md = cd;
    #pragma unroll
    for (int it = 0; it < 5; ++it) {             // A^(2^5) = A^32
        const double na = Ma * Ma + Mb * Mc;
        const double nb = Ma * Mb + Mb * Md;
        const double nc = Mc * Ma + Md * Mc;
        const double nd = Mc * Mb + Md * Md;
        Ma = na; Mb = nb; Mc = nc; Md = nd;
    }
    double pos = 0.0, vel = 0.0;
    float* wb = w + (size_t)bm * 64 * 128;
    for (int c = 0; c < 64; ++c) {
        float* row = wb + c * 128;
        const double wp = (double)row[d];
        const double wv = (double)row[64 + d];
        row[d] = (float)pos;                     // entry state of chunk c
        row[64 + d] = (float)vel;
        const double np = Ma * pos + Mb * vel + wp;
        const double nv = Mc * pos + Md * vel + wv;
        pos = np; vel = nv;
    }
}

// ---------------------------------------------------------------------------
// K1c: sim pass 2 — 32-step emit from precomputed entry state, two 16-ts
// quarter stages. LDS 8.9 KB.  [r10-verified]
// ---------------------------------------------------------------------------
__global__ __launch_bounds__(64) void sim_pass2(const float* __restrict__ forces,
                                                const float* __restrict__ hmod,
                                                const float* __restrict__ home,
                                                const float* __restrict__ masses,
                                                const float* __restrict__ tensions,
                                                const float* __restrict__ gains,
                                                const float* __restrict__ mics,
                                                const float* __restrict__ w,
                                                float* __restrict__ disp,
                                                float* __restrict__ rec) {
    const int blk = blockIdx.x;
    const int bm = blk >> 6, c = blk & 63;
    const int m = bm & 31;
    const int d = threadIdx.x;
    const int t0 = c * 32;
    __shared__ __align__(16) float ft[64][17];
    __shared__ __align__(16) float ht[64][17];
    const float k = tensions[m * 64 + d] / masses[m];
    const float gain = gains[m];
    const float mic = mics[m * 64 + d];
    const float hd = home[d];

    float pos = w[(size_t)blk * 128 + d];
    float vel = w[(size_t)blk * 128 + 64 + d];

    #pragma unroll
    for (int phase = 0; phase < 2; ++phase) {
        const int t0p = t0 + phase * 16;
        for (int i = d; i < 256; i += 64) {
            const int dd = i >> 2, q = (i & 3) * 4;
            const size_t off = ((size_t)bm * 64 + dd) * 2048 + t0p + q;
            *(float4*)&ft[dd][q] = *(const float4*)(forces + off);
            *(float4*)&ht[dd][q] = *(const float4*)(hmod + off);
        }
        __syncthreads();
        #pragma unroll
        for (int ts = 0; ts < 16; ++ts) {
            const float f = ft[d][ts];
            const float h = hd + ht[d][ts];
            const float dir = h - pos;
            const float acc = f + k * dir;
            vel = (vel + acc) * DAMP;
            pos = pos + vel;
            ft[d][ts] = dir;                        // disp tile (in place)
            const float x = vel * gain;
            const float e = __expf(2.f * x);
            ht[d][ts] = (1.f - 2.f / (e + 1.f)) * mic;   // prod tile (in place)
        }
        __syncthreads();
        for (int i = d; i < 256; i += 64) {
            const int dd = i >> 2, q = (i & 3) * 4;
            const size_t off = ((size_t)bm * 64 + dd) * 2048 + t0p + q;
            *(float4*)(disp + off) = *(float4*)&ft[dd][q];
        }
        {
            const int ts = d & 15, part = d >> 4;
            float s = 0.f;
            #pragma unroll
            for (int j = 0; j < 16; ++j) s += ht[16 * part + j][ts];
            s += __shfl_xor(s, 16);
            s += __shfl_xor(s, 32);
            if (d < 16) rec[(size_t)bm * 2048 + t0p + d] = s;
        }
        __syncthreads();
    }
}

// ---------------------------------------------------------------------------
// K2: mixture (fp32 acc -> bf16). [r9-verified]
// ---------------------------------------------------------------------------
__global__ __launch_bounds__(256) void mix_kernel(const float* __restrict__ disp,
                                                  const float* __restrict__ tofm,
                                                  unsigned short* __restrict__ mixture) {
    __shared__ __align__(16) float tf[64][16];
    const int tid = threadIdx.x;
    for (int i = tid; i < 1024; i += 256) tf[i >> 4][i & 15] = tofm[i];
    __syncthreads();
    const int bm = blockIdx.y;
    const int t = blockIdx.x * 256 + tid;
    float acc[16];
    #pragma unroll
    for (int f = 0; f < 16; ++f) acc[f] = 0.f;
    for (int d = 0; d < 64; ++d) {
        const float v = disp[((size_t)bm * 64 + d) * 2048 + t];
        const float4* r4 = (const float4*)tf[d];
        const float4 a4 = r4[0], b4 = r4[1], c4 = r4[2], d4 = r4[3];
        acc[0]  += v * a4.x; acc[1]  += v * a4.y; acc[2]  += v * a4.z; acc[3]  += v * a4.w;
        acc[4]  += v * b4.x; acc[5]  += v * b4.y; acc[6]  += v * b4.z; acc[7]  += v * b4.w;
        acc[8]  += v * c4.x; acc[9]  += v * c4.y; acc[10] += v * c4.z; acc[11] += v * c4.w;
        acc[12] += v * d4.x; acc[13] += v * d4.y; acc[14] += v * d4.z; acc[15] += v * d4.w;
    }
    #pragma unroll
    for (int f = 0; f < 16; ++f)
        mixture[((size_t)bm * 16 + f) * 2048 + t] = f2bf(acc[f]);
}

// ---------------------------------------------------------------------------
// K3 (MFMA): fft_resample — 2-chunk DirRev staging, bf16 up output.
// [unchanged r14]
// ---------------------------------------------------------------------------
#define DR_STRIDE 2064u           // 1024 bf16 + 16B pad; == 16 mod 128
#define W_STRIDE  5136u
#define W_OFF     33024u          // 16*2064
#define RS_SMEM   74112u          // + 8*5136

__global__ __launch_bounds__(256) void resample_kernel(const float* __restrict__ rec,
                                                       const unsigned short* __restrict__ dirrev,
                                                       unsigned short* __restrict__ upb) {
    const int bm = blockIdx.x;
    const int Q0 = blockIdx.y * 512;
    const int tid = threadIdx.x;
    __shared__ __align__(16) unsigned char smem[RS_SMEM];

    for (int x = tid; x < 2560; x += 256) {
        const int g = (Q0 + x + 1) & 2047;
        const unsigned short bv = f2bf(rec[(size_t)bm * 2048 + g]);
        #pragma unroll
        for (int sg = 0; sg < 8; ++sg) {
            const int y = x - sg;
            if (y >= 0) *(unsigned short*)(smem + W_OFF + sg * W_STRIDE + 2 * y) = bv;
        }
    }

    const int lane = tid & 63;
    const int wv = tid >> 6;
    const int i15 = lane & 15;
    const int g4 = lane >> 4;

    f32x4 acc[8];
    #pragma unroll
    for (int i = 0; i < 8; ++i) acc[i] = (f32x4){0.f, 0.f, 0.f, 0.f};

    const unsigned abase = (unsigned)i15 * DR_STRIDE + 16u * g4;
    const unsigned bbase = W_OFF + (unsigned)(i15 & 7) * W_STRIDE + 16u * (i15 >> 3) + 16u * g4;

    for (int kc = 0; kc < 2; ++kc) {
        if (kc) __syncthreads();
        for (int i = tid; i < 2048; i += 256) {
            const int p = i >> 7, c16 = i & 127;
            *(uint4*)(smem + (unsigned)p * DR_STRIDE + 16u * c16) =
                *(const uint4*)(dirrev + (size_t)p * 2048 + kc * 1024 + 8 * c16);
        }
        __syncthreads();

        for (int kkb = 0; kkb < 4; ++kkb) {
            bf16x8 afr[8];
            #pragma unroll
            for (int kj = 0; kj < 8; ++kj)
                afr[kj] = *(const bf16x8*)(smem + abase + 64u * (kkb * 8 + kj));
            #pragma unroll
            for (int qtl = 0; qtl < 8; ++qtl) {
                const int qt = wv * 8 + qtl;
                const unsigned bb = bbase + 32u * qt + 2048u * kc;
                #pragma unroll
                for (int kj = 0; kj < 8; ++kj) {
                    const bf16x8 bfr = *(const bf16x8*)(smem + bb + 64u * (kkb * 8 + kj));
                    acc[qtl] = __builtin_amdgcn_mfma_f32_16x16x32_bf16(afr[kj], bfr, acc[qtl], 0, 0, 0);
                }
            }
        }
    }

    #pragma unroll
    for (int qtl = 0; qtl < 8; ++qtl) {
        const int qt = wv * 8 + qtl;
        const int q = Q0 + 16 * qt + i15;
        const int sbase = 16 * q + 4 * g4;
        const unsigned jb = (unsigned)bm * 32768u + (unsigned)sbase;
        u16x4 o;
        o[0] = f2bf(fabsf(acc[qtl][0] * (1.f / 8192.f)) * noise_at(jb));
        o[1] = f2bf(fabsf(acc[qtl][1] * (1.f / 8192.f)) * noise_at(jb + 1u));
        o[2] = f2bf(fabsf(acc[qtl][2] * (1.f / 8192.f)) * noise_at(jb + 2u));
        o[3] = f2bf(fabsf(acc[qtl][3] * (1.f / 8192.f)) * noise_at(jb + 3u));
        *(u16x4*)(upb + (size_t)bm * 32768 + sbase) = o;
    }
}

// ---------------------------------------------------------------------------
// K4 (MFMA): hf — rolling B-fragment buffer (r15-verified) + PAIRED mixl:
// mixp[f][tt] = u32(m[t] | m[t+1]<<16) with zero-pad at t=2048, so each
// lerp is ONE ds_read_b32 instead of two ds_read_u16. Exact: posf is clamped
// to 2047 before floor, so whenever i1 would clamp (i0=2047), wg==0 and the
// padded high half contributes nothing. VGPR must stay <=64 (r16 cliff).
// grid (32 s-tiles of 1024, 64 bm), 256 threads.
// ---------------------------------------------------------------------------
#define W_STR2   3088u            // 1544 bf16, padded (1536 used)
#define MX_OFF   24704u           // 8*3088
#define HF_SMEM  29120u           // + 16*68*4 + pad

__global__ __launch_bounds__(256) void hf_kernel(const unsigned short* __restrict__ upb,
                                                 const unsigned short* __restrict__ fnrev,
                                                 const unsigned short* __restrict__ mixture,
                                                 float* __restrict__ hf) {
    const int tile = blockIdx.x;     // 0..31
    const int bm = blockIdx.y;       // 0..63
    const int b = bm >> 5;
    const int S0 = tile * 1024;
    const int tbase = tile * 64 - 1;
    const int tid = threadIdx.x;

    __shared__ __align__(16) unsigned char smem[HF_SMEM];
    unsigned* mixp = (unsigned*)(smem + MX_OFF);     // 16 x 68 u32 pairs

    // stage 8 shifted copies: W[x] = upb[S0-511+x], x in [0,1536)
    for (int x = tid; x < 1536; x += 256) {
        const int gidx = S0 - 511 + x;
        const unsigned short v = (gidx >= 0) ? upb[(size_t)bm * 32768 + gidx]
                                             : (unsigned short)0;
        #pragma unroll
        for (int sg = 0; sg < 8; ++sg) {
            const int y = x - sg;
            if (y >= 0) *(unsigned short*)(smem + sg * W_STR2 + 2 * y) = v;
        }
    }
    // stage mixl pairs (u32): mixp[f][tt] = (m[t], m[t+1]), t = tbase+tt
    for (int i = tid; i < 16 * 66; i += 256) {
        const int f = i / 66, tt = i - f * 66;
        const int t = tbase + tt;
        const unsigned short* mrow = mixture + ((size_t)bm * 16 + f) * 2048;
        const unsigned m0 = (t >= 0 && t < 2048) ? mrow[t] : 0u;
        const unsigned m1 = (t + 1 >= 0 && t + 1 < 2048) ? mrow[t + 1] : 0u;
        mixp[f * 68 + tt] = m0 | (m1 << 16);
    }
    // A-fragments from fnrev (L2-cached, 16B aligned loads)
    const int lane = tid & 63;
    const int i15 = lane & 15;
    const int g4 = lane >> 4;
    const int wv = tid >> 6;
    bf16x8 afr[16];
    #pragma unroll
    for (int kk = 0; kk < 16; ++kk)
        afr[kk] = *(const bf16x8*)(fnrev + (size_t)(b * 16 + i15) * 512 + 32 * kk + 8 * g4);
    __syncthreads();

    for (int rr = 0; rr < 4; ++rr) {
        const int rho = wv * 4 + rr;            // s residue 0..15
        const int sig = rho & 7;
        const unsigned baseR = (unsigned)sig * W_STR2 + 2u * (rho - sig)
                             + 32u * i15 + 16u * g4;
        // rolling window fragment buffer: frag j lives in slot j & 15
        bf16x8 wfr[16];
        #pragma unroll
        for (int j = 0; j < 8; ++j)
            wfr[j] = *(const bf16x8*)(smem + baseR + 64u * j);
        #pragma unroll
        for (int g = 0; g < 4; ++g) {
            #pragma unroll
            for (int jj = 0; jj < 8; ++jj) {
                const int j = 8 * g + 8 + jj;
                wfr[j & 15] = *(const bf16x8*)(smem + baseR + 64u * (unsigned)j);
            }
            f32x4 acc = {0.f, 0.f, 0.f, 0.f};
            #pragma unroll
            for (int kk = 0; kk < 16; ++kk)
                acc = __builtin_amdgcn_mfma_f32_16x16x32_bf16(afr[kk], wfr[(8 * g + kk) & 15], acc, 0, 0, 0);
            const int s = S0 + 256 * g + rho + 16 * i15;
            float posf = ((float)s + 0.5f) * 0.0625f - 0.5f;
            posf = fminf(fmaxf(posf, 0.f), 2047.f);
            const int i0 = (int)posf;
            const float wg = posf - (float)i0;
            const int t0 = i0 - tbase;
            float part = 0.f;
            #pragma unroll
            for (int r = 0; r < 4; ++r) {
                const int f = 4 * g4 + r;
                const unsigned pm = mixp[f * 68 + t0];
                const float lo = bf2f((unsigned short)(pm & 0xFFFFu));
                const float hi = bf2f((unsigned short)(pm >> 16));
                const float mv = lo * (1.f - wg) + hi * wg;
                part += mv * acc[r];
            }
            part += __shfl_xor(part, 16);
            part += __shfl_xor(part, 32);
            if (g4 == 0) {
                const int e = 511 + 256 * g + rho + 16 * i15;   // copy-0 element
                const float upv = bf2f(*(const unsigned short*)(smem + 2 * e));
                hf[(size_t)bm * 32768 + s] = part + upv;
            }
        }
    }
}

// ---------------------------------------------------------------------------
// Launch
// ---------------------------------------------------------------------------
extern "C" void kernel_launch(void* const* d_in, const int* in_sizes, int n_in,
                              void* d_out, int out_size, void* d_ws, size_t ws_size,
                              hipStream_t stream) {
    const float* forces   = (const float*)d_in[0];
    const float* hmod     = (const float*)d_in[1];
    const float* filters  = (const float*)d_in[2];
    const float* home     = (const float*)d_in[3];
    const float* masses   = (const float*)d_in[4];
    const float* tensions = (const float*)d_in[5];
    const float* gains    = (const float*)d_in[6];
    const float* mics     = (const float*)d_in[7];
    const float* tofm     = (const float*)d_in[8];

    float* out  = (float*)d_out;
    float* rec  = out;                  // 131072
    float* disp = out + 131072;         // 8388608
    float* hf   = out + 8519680;        // 2097152

    unsigned short* upb     = (unsigned short*)d_ws;                    // 2097152 bf16 (4MB)
    unsigned short* mixture = (unsigned short*)((float*)d_ws + 1048576);// 2097152 bf16 (4MB)
    unsigned short* dirrev  = (unsigned short*)((float*)d_ws + 2097152);// 32768 bf16
    float* w                = (float*)d_ws + 2113536;                   // 524288 f32 (2MB)
    unsigned short* fnrev   = (unsigned short*)((float*)d_ws + 2637824);// 16384 bf16
    // total ws use ~10.2 MB

    sim_pass1<<<4640, 64, 0, stream>>>(forces, hmod, home, masses, tensions, w,
                                       filters, dirrev, fnrev);
    sim_scan<<<64, 64, 0, stream>>>(masses, tensions, w);
    sim_pass2<<<4096, 64, 0, stream>>>(forces, hmod, home, masses, tensions, gains, mics, w, disp, rec);
    mix_kernel<<<dim3(8, 64), 256, 0, stream>>>(disp, tofm, mixture);
    resample_kernel<<<dim3(64, 4), 256, 0, stream>>>(rec, dirrev, upb);
    hf_kernel<<<dim3(32, 64), 256, 0, stream>>>(upb, fnrev, mixture, hf);
}